// Round 1
// baseline (323.080 us; speedup 1.0000x reference)
//
#include <hip/hip_runtime.h>
#include <hip/hip_bf16.h>
#include <cstdint>
#include <cstddef>

// Problem constants (fixed by the reference)
#define BATCH 128
#define SEQ   512
#define DIM   1024
#define MROWS (BATCH * SEQ)          // 65536

typedef short short8 __attribute__((ext_vector_type(8)));
typedef __bf16 bf16x8 __attribute__((ext_vector_type(8)));
typedef float f32x4 __attribute__((ext_vector_type(4)));

// ---------- MFMA wrapper: accept either builtin signature (short8 or bf16x8) ----------
template <typename VA> struct other_frag { using type = bf16x8; };
template <> struct other_frag<bf16x8> { using type = short8; };

template <typename VA>
__device__ __forceinline__ auto try_mfma(VA a, VA b, f32x4 c, int)
    -> decltype(__builtin_amdgcn_mfma_f32_16x16x32_bf16(a, b, c, 0, 0, 0)) {
  return __builtin_amdgcn_mfma_f32_16x16x32_bf16(a, b, c, 0, 0, 0);
}
template <typename VA>
__device__ __forceinline__ f32x4 try_mfma(VA a, VA b, f32x4 c, long) {
  using O = typename other_frag<VA>::type;
  O a2 = __builtin_bit_cast(O, a);
  O b2 = __builtin_bit_cast(O, b);
  return __builtin_amdgcn_mfma_f32_16x16x32_bf16(a2, b2, c, 0, 0, 0);
}
__device__ __forceinline__ f32x4 mfma_bf16(short8 a, short8 b, f32x4 c) {
  return try_mfma(a, b, c, 0);
}

// ---------- helpers ----------
__device__ __forceinline__ unsigned short f32_to_bf16(float f) {
  union { float f; uint32_t u; } v; v.f = f;
  uint32_t u = v.u;
  u += 0x7FFFu + ((u >> 16) & 1u);   // round-to-nearest-even
  return (unsigned short)(u >> 16);
}

__device__ __forceinline__ void gload_lds16(const void* g, void* l) {
  __builtin_amdgcn_global_load_lds(
      (__attribute__((address_space(1))) void*)g,
      (__attribute__((address_space(3))) void*)l,
      16, 0, 0);
}

__device__ __forceinline__ float fast_tanh(float x) {
  x = fminf(fmaxf(x, -15.0f), 15.0f);
  float e = __expf(2.0f * x);
  return (e - 1.0f) / (e + 1.0f);
}

// ---------- kernel 1: cast X fp32 -> bf16 ----------
__global__ __launch_bounds__(256) void cast_x_kernel(const float* __restrict__ X,
                                                     unsigned short* __restrict__ Xb) {
  const int total8 = MROWS * DIM / 8;        // 8388608 groups of 8
  int idx = blockIdx.x * 256 + threadIdx.x;
  const int stride = 2048 * 256;
  for (int i = idx; i < total8; i += stride) {
    const f32x4* p = (const f32x4*)X + (size_t)i * 2;
    f32x4 a = p[0];
    f32x4 b = p[1];
    short8 o;
    o[0] = (short)f32_to_bf16(a[0]); o[1] = (short)f32_to_bf16(a[1]);
    o[2] = (short)f32_to_bf16(a[2]); o[3] = (short)f32_to_bf16(a[3]);
    o[4] = (short)f32_to_bf16(b[0]); o[5] = (short)f32_to_bf16(b[1]);
    o[6] = (short)f32_to_bf16(b[2]); o[7] = (short)f32_to_bf16(b[3]);
    *((short8*)Xb + i) = o;
  }
}

// ---------- kernel 2: W1 (D x D) -> W1t bf16 (transposed, [e][d]) ----------
__global__ __launch_bounds__(256) void w1t_kernel(const float* __restrict__ W1,
                                                  unsigned short* __restrict__ W1t) {
  __shared__ float tile[64][65];
  int bx = blockIdx.x & 15;    // e-tile
  int by = blockIdx.x >> 4;    // d-tile
  int t = threadIdx.x;
  int c = t & 63, r0 = t >> 6;
#pragma unroll
  for (int i = 0; i < 16; i++) {
    int r = i * 4 + r0;
    tile[r][c] = W1[(size_t)(by * 64 + r) * DIM + bx * 64 + c];
  }
  __syncthreads();
#pragma unroll
  for (int i = 0; i < 16; i++) {
    int r = i * 4 + r0;
    // W1t[e][d] = W1[d][e];  e = bx*64 + r, d = by*64 + c
    W1t[(size_t)(bx * 64 + r) * DIM + by * 64 + c] = f32_to_bf16(tile[c][r]);
  }
}

// ---------- kernel 3: u_last = X[:, -1, :] ----------
__global__ __launch_bounds__(256) void ulast_kernel(const float* __restrict__ X,
                                                    float* __restrict__ u_last) {
  int i = blockIdx.x * 256 + threadIdx.x;          // 32768 float4s
  int b = i >> 8;                                   // 256 float4 per row
  int d4 = i & 255;
  ((f32x4*)u_last)[i] = ((const f32x4*)X)[((size_t)b * SEQ + (SEQ - 1)) * 256 + d4];
}

// ---------- kernel 4: fused GEMM + tanh + w2-dot -> scores (atomicAdd) ----------
// C[m][e] = sum_d Xb[m][d] * W1t[e][d];  scores[m] += sum_e tanh(C+b1[e]) * w2[e]
#define BM 128
#define BN 128
#define BK 32

__global__ __launch_bounds__(256, 2) void gemm_score_kernel(
    const unsigned short* __restrict__ Xb,    // [MROWS][DIM]
    const unsigned short* __restrict__ W1t,   // [DIM][DIM]  (e-major)
    const float* __restrict__ b1,
    const float* __restrict__ w2,
    float* __restrict__ scores) {             // [MROWS]
  __shared__ unsigned short As[BM * BK];      // [128][32]
  __shared__ unsigned short Bs[BN * BK];

  const int bx = blockIdx.x;                  // 4096 = 512 m-tiles * 8 n-tiles
  const int m0 = (bx & 511) * BM;             // same-m blocks land on same XCD (bx%8 == m%8)
  const int n0 = (bx >> 9) * BN;
  const int tid = threadIdx.x;
  const int lane = tid & 63;
  const int wave = tid >> 6;                  // 0..3
  const int wr = wave >> 1, wc = wave & 1;    // 2x2 waves, 64x64 out each

  f32x4 acc[4][4];
#pragma unroll
  for (int mi = 0; mi < 4; mi++)
#pragma unroll
    for (int ni = 0; ni < 4; ni++)
      acc[mi][ni] = (f32x4){0.f, 0.f, 0.f, 0.f};

  // staging addresses: per global_load_lds inst, lane l writes LDS base + l*16B.
  // layout [row][k]: lane l -> row = l>>2, k = (l&3)*8  (row stride 32 shorts = 64B)
  const size_t aBase = (size_t)(m0 + wave * 32 + (lane >> 2)) * DIM + (lane & 3) * 8;
  const size_t bBase = (size_t)(n0 + wave * 32 + (lane >> 2)) * DIM + (lane & 3) * 8;
  unsigned short* ldsA0 = &As[(wave * 32) * BK];
  unsigned short* ldsA1 = &As[(wave * 32 + 16) * BK];
  unsigned short* ldsB0 = &Bs[(wave * 32) * BK];
  unsigned short* ldsB1 = &Bs[(wave * 32 + 16) * BK];

  const int krow = lane & 15;                 // M-row (A) / N-col (B) within fragment
  const int kofs = (lane >> 4) * 8;           // k offset within fragment
  const int aOff = (wr * 64 + krow) * BK + kofs;
  const int bOff = (wc * 64 + krow) * BK + kofs;

  for (int kt = 0; kt < DIM; kt += BK) {
    gload_lds16(Xb + aBase + kt, ldsA0);
    gload_lds16(Xb + aBase + 16 * DIM + kt, ldsA1);
    gload_lds16(W1t + bBase + kt, ldsB0);
    gload_lds16(W1t + bBase + 16 * DIM + kt, ldsB1);
    __syncthreads();   // compiler drains vmcnt before barrier

    short8 af[4], bfr[4];
#pragma unroll
    for (int mi = 0; mi < 4; mi++)
      af[mi] = *(const short8*)&As[aOff + mi * 16 * BK];
#pragma unroll
    for (int ni = 0; ni < 4; ni++)
      bfr[ni] = *(const short8*)&Bs[bOff + ni * 16 * BK];
#pragma unroll
    for (int mi = 0; mi < 4; mi++)
#pragma unroll
      for (int ni = 0; ni < 4; ni++)
        acc[mi][ni] = mfma_bf16(af[mi], bfr[ni], acc[mi][ni]);
    __syncthreads();
  }

  // epilogue: scores[row] += sum over this wave's 64 cols of tanh(c + b1) * w2
  const int cg = lane >> 4;   // row group: rows cg*4 + r
  const int cl = lane & 15;   // col within fragment
#pragma unroll
  for (int mi = 0; mi < 4; mi++) {
    float p0 = 0.f, p1 = 0.f, p2 = 0.f, p3 = 0.f;
#pragma unroll
    for (int ni = 0; ni < 4; ni++) {
      int col = n0 + wc * 64 + ni * 16 + cl;
      float w2v = w2[col];
      float b1v = b1[col];
      p0 += fast_tanh(acc[mi][ni][0] + b1v) * w2v;
      p1 += fast_tanh(acc[mi][ni][1] + b1v) * w2v;
      p2 += fast_tanh(acc[mi][ni][2] + b1v) * w2v;
      p3 += fast_tanh(acc[mi][ni][3] + b1v) * w2v;
    }
#pragma unroll
    for (int off = 1; off < 16; off <<= 1) {
      p0 += __shfl_xor(p0, off);
      p1 += __shfl_xor(p1, off);
      p2 += __shfl_xor(p2, off);
      p3 += __shfl_xor(p3, off);
    }
    if (cl == 0) {
      int row = m0 + wr * 64 + mi * 16 + cg * 4;
      atomicAdd(&scores[row + 0], p0);
      atomicAdd(&scores[row + 1], p1);
      atomicAdd(&scores[row + 2], p2);
      atomicAdd(&scores[row + 3], p3);
    }
  }
}

// ---------- kernel 5: masked softmax + u_att ----------
__global__ __launch_bounds__(256) void attn_uatt_kernel(
    const float* __restrict__ X,
    const float* __restrict__ scores,
    const int* __restrict__ mask,
    float* __restrict__ u_att) {
  const int b = blockIdx.x;
  const int half = blockIdx.y;            // d-range [half*512, half*512+512)
  const int tid = threadIdx.x;
  const int lane = tid & 63;
  const int wave = tid >> 6;

  __shared__ float attn[SEQ];
  __shared__ float rbuf[4];
  __shared__ f32x4 comb[128];

  float s0 = scores[(size_t)b * SEQ + tid];
  float s1 = scores[(size_t)b * SEQ + 256 + tid];
  if (mask[(size_t)b * SEQ + tid]) s0 = -1000000000.0f;
  if (mask[(size_t)b * SEQ + 256 + tid]) s1 = -1000000000.0f;

  float mx = fmaxf(s0, s1);
#pragma unroll
  for (int off = 1; off < 64; off <<= 1) mx = fmaxf(mx, __shfl_xor(mx, off));
  if (lane == 0) rbuf[wave] = mx;
  __syncthreads();
  mx = fmaxf(fmaxf(rbuf[0], rbuf[1]), fmaxf(rbuf[2], rbuf[3]));

  float p0 = expf(s0 - mx), p1 = expf(s1 - mx);
  float sm = p0 + p1;
#pragma unroll
  for (int off = 1; off < 64; off <<= 1) sm += __shfl_xor(sm, off);
  __syncthreads();                 // everyone done reading rbuf (max phase)
  if (lane == 0) rbuf[wave] = sm;
  __syncthreads();
  sm = rbuf[0] + rbuf[1] + rbuf[2] + rbuf[3];
  float inv = 1.0f / sm;
  attn[tid] = p0 * inv;
  attn[tid + 256] = p1 * inv;
  __syncthreads();

  // u_att[b][d] = sum_s attn[s] * X[b][s][d] ; this block covers 512 d's (128 float4)
  const int col = tid & 127;           // float4 column within the half
  const int sh = tid >> 7;             // s-range split: [sh*256, sh*256+256)
  const f32x4* Xp = (const f32x4*)X + (size_t)b * SEQ * 256 + half * 128 + col;
  f32x4 a4 = {0.f, 0.f, 0.f, 0.f};
#pragma unroll 4
  for (int s = sh * 256; s < sh * 256 + 256; s++) {
    a4 += attn[s] * Xp[(size_t)s * 256];
  }
  if (sh == 1) comb[col] = a4;
  __syncthreads();
  if (sh == 0) {
    a4 += comb[col];
    ((f32x4*)u_att)[(size_t)b * 256 + half * 128 + col] = a4;
  }
}

// ---------- launcher ----------
extern "C" void kernel_launch(void* const* d_in, const int* in_sizes, int n_in,
                              void* d_out, int out_size, void* d_ws, size_t ws_size,
                              hipStream_t stream) {
  const float* X    = (const float*)d_in[0];   // [128][512][1024] fp32
  const int*   mask = (const int*)d_in[1];     // [128][512] int32 (bool)
  const float* W1   = (const float*)d_in[2];   // [1024][1024]
  const float* b1   = (const float*)d_in[3];   // [1024]
  const float* w2   = (const float*)d_in[4];   // [1024]

  float* out    = (float*)d_out;
  float* u_last = out;                          // [128][1024]
  float* u_att  = out + BATCH * DIM;            // [128][1024]

  char* ws = (char*)d_ws;
  unsigned short* Xb  = (unsigned short*)ws;                                // 128 MB
  unsigned short* W1t = (unsigned short*)(ws + (size_t)MROWS * DIM * 2);    // 2 MB
  float* scores = (float*)(ws + (size_t)MROWS * DIM * 2 + (size_t)DIM * DIM * 2); // 256 KB

  hipMemsetAsync(scores, 0, MROWS * sizeof(float), stream);
  hipLaunchKernelGGL(cast_x_kernel, dim3(2048), dim3(256), 0, stream, X, Xb);
  hipLaunchKernelGGL(w1t_kernel, dim3(256), dim3(256), 0, stream, W1, W1t);
  hipLaunchKernelGGL(ulast_kernel, dim3(128), dim3(256), 0, stream, X, u_last);
  hipLaunchKernelGGL(gemm_score_kernel, dim3(4096), dim3(256), 0, stream,
                     Xb, W1t, b1, w2, scores);
  hipLaunchKernelGGL(attn_uatt_kernel, dim3(128, 2), dim3(256), 0, stream,
                     X, scores, mask, u_att);
}

// Round 2
// 266.600 us; speedup vs baseline: 1.2119x; 1.2119x over previous
//
#include <hip/hip_runtime.h>
#include <hip/hip_bf16.h>
#include <cstdint>
#include <cstddef>

// Problem constants (fixed by the reference)
#define BATCH 128
#define SEQ   512
#define DIM   1024
#define MROWS (BATCH * SEQ)          // 65536
#define NT    32                     // K sub-tiles of 32 (DIM/32)

typedef short short8 __attribute__((ext_vector_type(8)));
typedef __bf16 bf16x8 __attribute__((ext_vector_type(8)));
typedef float f32x4 __attribute__((ext_vector_type(4)));

// ---------- MFMA wrapper: accept either builtin signature (short8 or bf16x8) ----------
template <typename VA> struct other_frag { using type = bf16x8; };
template <> struct other_frag<bf16x8> { using type = short8; };

template <typename VA>
__device__ __forceinline__ auto try_mfma(VA a, VA b, f32x4 c, int)
    -> decltype(__builtin_amdgcn_mfma_f32_16x16x32_bf16(a, b, c, 0, 0, 0)) {
  return __builtin_amdgcn_mfma_f32_16x16x32_bf16(a, b, c, 0, 0, 0);
}
template <typename VA>
__device__ __forceinline__ f32x4 try_mfma(VA a, VA b, f32x4 c, long) {
  using O = typename other_frag<VA>::type;
  O a2 = __builtin_bit_cast(O, a);
  O b2 = __builtin_bit_cast(O, b);
  return __builtin_amdgcn_mfma_f32_16x16x32_bf16(a2, b2, c, 0, 0, 0);
}
__device__ __forceinline__ f32x4 mfma_bf16(short8 a, short8 b, f32x4 c) {
  return try_mfma(a, b, c, 0);
}

// ---------- helpers ----------
__device__ __forceinline__ unsigned short f32_to_bf16(float f) {
  union { float f; uint32_t u; } v; v.f = f;
  uint32_t u = v.u;
  u += 0x7FFFu + ((u >> 16) & 1u);   // round-to-nearest-even
  return (unsigned short)(u >> 16);
}

__device__ __forceinline__ float bf16_to_f32(unsigned short u) {
  union { uint32_t u; float f; } v; v.u = ((uint32_t)u) << 16; return v.f;
}

__device__ __forceinline__ void gload_lds16(const void* g, void* l) {
  __builtin_amdgcn_global_load_lds(
      (__attribute__((address_space(1))) void*)g,
      (__attribute__((address_space(3))) void*)l,
      16, 0, 0);
}

__device__ __forceinline__ float fast_tanh(float x) {
  x = fminf(fmaxf(x, -15.0f), 15.0f);
  float e = __expf(2.0f * x);
  return (e - 1.0f) / (e + 1.0f);
}

// ---------- kernel 1: cast X fp32 -> bf16 ----------
__global__ __launch_bounds__(256) void cast_x_kernel(const float* __restrict__ X,
                                                     unsigned short* __restrict__ Xb) {
  const int total8 = MROWS * DIM / 8;        // 8388608 groups of 8
  int idx = blockIdx.x * 256 + threadIdx.x;
  const int stride = 2048 * 256;
  for (int i = idx; i < total8; i += stride) {
    const f32x4* p = (const f32x4*)X + (size_t)i * 2;
    f32x4 a = p[0];
    f32x4 b = p[1];
    short8 o;
    o[0] = (short)f32_to_bf16(a[0]); o[1] = (short)f32_to_bf16(a[1]);
    o[2] = (short)f32_to_bf16(a[2]); o[3] = (short)f32_to_bf16(a[3]);
    o[4] = (short)f32_to_bf16(b[0]); o[5] = (short)f32_to_bf16(b[1]);
    o[6] = (short)f32_to_bf16(b[2]); o[7] = (short)f32_to_bf16(b[3]);
    *((short8*)Xb + i) = o;
  }
}

// ---------- kernel 2: W1 (D x D) -> W1t bf16 (transposed, [e][d]) ----------
__global__ __launch_bounds__(256) void w1t_kernel(const float* __restrict__ W1,
                                                  unsigned short* __restrict__ W1t) {
  __shared__ float tile[64][65];
  int bx = blockIdx.x & 15;    // e-tile
  int by = blockIdx.x >> 4;    // d-tile
  int t = threadIdx.x;
  int c = t & 63, r0 = t >> 6;
#pragma unroll
  for (int i = 0; i < 16; i++) {
    int r = i * 4 + r0;
    tile[r][c] = W1[(size_t)(by * 64 + r) * DIM + bx * 64 + c];
  }
  __syncthreads();
#pragma unroll
  for (int i = 0; i < 16; i++) {
    int r = i * 4 + r0;
    W1t[(size_t)(bx * 64 + r) * DIM + by * 64 + c] = f32_to_bf16(tile[c][r]);
  }
}

// ---------- kernel 3: u_last = X[:, -1, :] ----------
__global__ __launch_bounds__(256) void ulast_kernel(const float* __restrict__ X,
                                                    float* __restrict__ u_last) {
  int i = blockIdx.x * 256 + threadIdx.x;          // 32768 float4s
  int b = i >> 8;
  int d4 = i & 255;
  ((f32x4*)u_last)[i] = ((const f32x4*)X)[((size_t)b * SEQ + (SEQ - 1)) * 256 + d4];
}

// ---------- kernel 4: 256x256-tile pipelined GEMM + tanh + w2-dot -> scores ----------
// C[m][e] = sum_d Xb[m][d] * W1t[e][d];  scores[m] += sum_e tanh(C+b1[e]) * w2[e]
//
// 8 waves (2M x 4N), per-wave output 128x64. K pipelined in sub-tiles of 32
// with a depth-4 LDS ring (4 x (16KB A + 16KB B) = 128 KB). One raw s_barrier
// + counted vmcnt(8) per sub-tile; tail peeled with vmcnt(4)/vmcnt(0).
//
// LDS layout per sub-tile buffer ([256 rows][32 k] bf16, 16 KB):
//   row pairs packed into 128-B stored rows; 16-B chunk index within the
//   stored row = ((row&1)*4 + k16) ^ (srow&7)  (srow = row>>1).
//   -> every 16-lane ds_read_b128 frag group hits each bank-quad exactly 2x.
// Staging writes LDS linearly (global_load_lds) and applies the inverse
// (same) permutation to the *global* source address.
__global__ __launch_bounds__(512, 2) void gemm_score_kernel(
    const unsigned short* __restrict__ Xb,    // [MROWS][DIM]
    const unsigned short* __restrict__ W1t,   // [DIM][DIM]  (e-major)
    const float* __restrict__ b1,
    const float* __restrict__ w2,
    float* __restrict__ scores) {             // [MROWS]
  __shared__ __align__(16) char lds[131072];  // A: [0,64K), B: [64K,128K)

  const int tid = threadIdx.x;
  const int lane = tid & 63;
  const int w = tid >> 6;                     // wave 0..7
  const int wr = w >> 2, wc = w & 3;          // 2 x 4 wave grid

  // chunked XCD swizzle: 1024 blocks, 8 XCDs, n-fastest within each chunk
  const int bx = blockIdx.x;
  const int swz = (bx & 7) * 128 + (bx >> 3);
  const int m0 = (swz >> 2) * 256;
  const int n0 = (swz & 3) * 256;

  // ---- staging addresses.  chunk sc = (i*8+w)*64 + lane, LDS byte = sc*16.
  // inverse map: srow = sc>>3, ic = sc&7, j = ic ^ (srow&7),
  //              row = srow*2 + (j>>2), k16 = j&3.
  const unsigned short *a0Src, *a1Src, *b0Src, *b1Src;
  {
    int sc0 = w * 64 + lane;
    int sr0 = sc0 >> 3, j0 = (sc0 & 7) ^ (sr0 & 7);
    int row0 = sr0 * 2 + (j0 >> 2), c40 = j0 & 3;
    a0Src = Xb  + (size_t)(m0 + row0) * DIM + c40 * 8;
    b0Src = W1t + (size_t)(n0 + row0) * DIM + c40 * 8;
    int sc1 = (8 + w) * 64 + lane;
    int sr1 = sc1 >> 3, j1 = (sc1 & 7) ^ (sr1 & 7);
    int row1 = sr1 * 2 + (j1 >> 2), c41 = j1 & 3;
    a1Src = Xb  + (size_t)(m0 + row1) * DIM + c41 * 8;
    b1Src = W1t + (size_t)(n0 + row1) * DIM + c41 * 8;
  }
  const int dst0 = w * 1024;          // wave-uniform LDS dest base (bytes)
  const int dst1 = (8 + w) * 1024;

  // ---- fragment LDS byte offsets (within a buffer)
  int aOff[8];
#pragma unroll
  for (int mi = 0; mi < 8; mi++) {
    int row = wr * 128 + mi * 16 + (lane & 15);
    int srow = row >> 1;
    int ic = ((row & 1) * 4 + (lane >> 4)) ^ (srow & 7);
    aOff[mi] = srow * 128 + ic * 16;
  }
  int bOff[4];
#pragma unroll
  for (int ni = 0; ni < 4; ni++) {
    int row = wc * 64 + ni * 16 + (lane & 15);
    int srow = row >> 1;
    int ic = ((row & 1) * 4 + (lane >> 4)) ^ (srow & 7);
    bOff[ni] = 65536 + srow * 128 + ic * 16;   // B region
  }

  f32x4 acc[8][4];
#pragma unroll
  for (int mi = 0; mi < 8; mi++)
#pragma unroll
    for (int ni = 0; ni < 4; ni++)
      acc[mi][ni] = (f32x4){0.f, 0.f, 0.f, 0.f};

#define STAGE(S) do {                                                   \
    const int bufS_ = ((S) & 3) * 16384;                                \
    const int ktS_ = (S) * 32;                                          \
    gload_lds16(a0Src + ktS_, lds + bufS_ + dst0);                      \
    gload_lds16(a1Src + ktS_, lds + bufS_ + dst1);                      \
    gload_lds16(b0Src + ktS_, lds + 65536 + bufS_ + dst0);              \
    gload_lds16(b1Src + ktS_, lds + 65536 + bufS_ + dst1);              \
  } while (0)

#define KITER(S, VMSTR) do {                                            \
    asm volatile("s_waitcnt vmcnt(" VMSTR ")" ::: "memory");            \
    __builtin_amdgcn_s_barrier();                                       \
    __builtin_amdgcn_sched_barrier(0);                                  \
    if ((S) + 3 < NT) STAGE((S) + 3);                                   \
    const int buf_ = ((S) & 3) * 16384;                                 \
    short8 af[8], bfv[4];                                               \
    _Pragma("unroll")                                                   \
    for (int mi = 0; mi < 8; mi++)                                      \
      af[mi] = *(const short8*)(lds + buf_ + aOff[mi]);                 \
    _Pragma("unroll")                                                   \
    for (int ni = 0; ni < 4; ni++)                                      \
      bfv[ni] = *(const short8*)(lds + buf_ + bOff[ni]);                \
    __builtin_amdgcn_s_setprio(1);                                      \
    _Pragma("unroll")                                                   \
    for (int mi = 0; mi < 8; mi++)                                      \
      _Pragma("unroll")                                                 \
      for (int ni = 0; ni < 4; ni++)                                    \
        acc[mi][ni] = mfma_bf16(af[mi], bfv[ni], acc[mi][ni]);          \
    __builtin_amdgcn_s_setprio(0);                                      \
  } while (0)

  // prologue: 3 sub-tiles in flight (12 wave-loads)
  STAGE(0); STAGE(1); STAGE(2);

  for (int s = 0; s < NT - 2; ++s) KITER(s, "8");
  KITER(NT - 2, "4");
  KITER(NT - 1, "0");

#undef STAGE
#undef KITER

  // epilogue: scores[row] += sum over this wave's 64 cols of tanh(c + b1) * w2
  const int cg = lane >> 4;   // row group: rows cg*4 + j
  const int cl = lane & 15;   // col within fragment
#pragma unroll
  for (int mi = 0; mi < 8; mi++) {
    float p0 = 0.f, p1 = 0.f, p2 = 0.f, p3 = 0.f;
#pragma unroll
    for (int ni = 0; ni < 4; ni++) {
      int col = n0 + wc * 64 + ni * 16 + cl;
      float w2v = w2[col];
      float b1v = b1[col];
      p0 += fast_tanh(acc[mi][ni][0] + b1v) * w2v;
      p1 += fast_tanh(acc[mi][ni][1] + b1v) * w2v;
      p2 += fast_tanh(acc[mi][ni][2] + b1v) * w2v;
      p3 += fast_tanh(acc[mi][ni][3] + b1v) * w2v;
    }
#pragma unroll
    for (int off = 1; off < 16; off <<= 1) {
      p0 += __shfl_xor(p0, off);
      p1 += __shfl_xor(p1, off);
      p2 += __shfl_xor(p2, off);
      p3 += __shfl_xor(p3, off);
    }
    if (cl == 0) {
      int row = m0 + wr * 128 + mi * 16 + cg * 4;
      atomicAdd(&scores[row + 0], p0);
      atomicAdd(&scores[row + 1], p1);
      atomicAdd(&scores[row + 2], p2);
      atomicAdd(&scores[row + 3], p3);
    }
  }
}

// ---------- kernel 5: masked softmax + u_att (reads bf16 Xb) ----------
__global__ __launch_bounds__(256) void attn_uatt_kernel(
    const unsigned short* __restrict__ Xb,
    const float* __restrict__ scores,
    const int* __restrict__ mask,
    float* __restrict__ u_att) {
  const int b = blockIdx.x;
  const int half = blockIdx.y;            // d-range [half*512, half*512+512)
  const int tid = threadIdx.x;
  const int lane = tid & 63;
  const int wave = tid >> 6;

  __shared__ float attn[SEQ];
  __shared__ float rbuf[4];
  __shared__ float part[3][64 * 9];       // padded stride 9

  float s0 = scores[(size_t)b * SEQ + tid];
  float s1 = scores[(size_t)b * SEQ + 256 + tid];
  if (mask[(size_t)b * SEQ + tid]) s0 = -1000000000.0f;
  if (mask[(size_t)b * SEQ + 256 + tid]) s1 = -1000000000.0f;

  float mx = fmaxf(s0, s1);
#pragma unroll
  for (int off = 1; off < 64; off <<= 1) mx = fmaxf(mx, __shfl_xor(mx, off));
  if (lane == 0) rbuf[wave] = mx;
  __syncthreads();
  mx = fmaxf(fmaxf(rbuf[0], rbuf[1]), fmaxf(rbuf[2], rbuf[3]));

  float p0 = expf(s0 - mx), p1 = expf(s1 - mx);
  float sm = p0 + p1;
#pragma unroll
  for (int off = 1; off < 64; off <<= 1) sm += __shfl_xor(sm, off);
  __syncthreads();
  if (lane == 0) rbuf[wave] = sm;
  __syncthreads();
  sm = rbuf[0] + rbuf[1] + rbuf[2] + rbuf[3];
  float inv = 1.0f / sm;
  attn[tid] = p0 * inv;
  attn[tid + 256] = p1 * inv;
  __syncthreads();

  // u_att[b][d] = sum_s attn[s] * X[b][s][d]; block covers 512 d (64 chunks of 8)
  const int col = tid & 63;            // 8-bf16 chunk within the half
  const int sh = tid >> 6;             // s-range split: [sh*128, sh*128+128)
  const short8* Xp = (const short8*)Xb + (size_t)b * SEQ * (DIM / 8) + half * 64 + col;
  float a[8] = {0.f, 0.f, 0.f, 0.f, 0.f, 0.f, 0.f, 0.f};
  for (int s = sh * 128; s < sh * 128 + 128; s++) {
    short8 v = Xp[(size_t)s * (DIM / 8)];
    float wgt = attn[s];
#pragma unroll
    for (int j = 0; j < 8; j++)
      a[j] += wgt * bf16_to_f32((unsigned short)v[j]);
  }
  if (sh) {
#pragma unroll
    for (int j = 0; j < 8; j++) part[sh - 1][col * 9 + j] = a[j];
  }
  __syncthreads();
  if (sh == 0) {
#pragma unroll
    for (int j = 0; j < 8; j++)
      a[j] += part[0][col * 9 + j] + part[1][col * 9 + j] + part[2][col * 9 + j];
    f32x4 lo = {a[0], a[1], a[2], a[3]};
    f32x4 hi = {a[4], a[5], a[6], a[7]};
    f32x4* dst = (f32x4*)(u_att + (size_t)b * DIM + half * 512 + col * 8);
    dst[0] = lo;
    dst[1] = hi;
  }
}

// ---------- launcher ----------
extern "C" void kernel_launch(void* const* d_in, const int* in_sizes, int n_in,
                              void* d_out, int out_size, void* d_ws, size_t ws_size,
                              hipStream_t stream) {
  const float* X    = (const float*)d_in[0];   // [128][512][1024] fp32
  const int*   mask = (const int*)d_in[1];     // [128][512] int32 (bool)
  const float* W1   = (const float*)d_in[2];   // [1024][1024]
  const float* b1   = (const float*)d_in[3];   // [1024]
  const float* w2   = (const float*)d_in[4];   // [1024]

  float* out    = (float*)d_out;
  float* u_last = out;                          // [128][1024]
  float* u_att  = out + BATCH * DIM;            // [128][1024]

  char* ws = (char*)d_ws;
  unsigned short* Xb  = (unsigned short*)ws;                                // 128 MB
  unsigned short* W1t = (unsigned short*)(ws + (size_t)MROWS * DIM * 2);    // 2 MB
  float* scores = (float*)(ws + (size_t)MROWS * DIM * 2 + (size_t)DIM * DIM * 2); // 256 KB

  hipMemsetAsync(scores, 0, MROWS * sizeof(float), stream);
  hipLaunchKernelGGL(cast_x_kernel, dim3(2048), dim3(256), 0, stream, X, Xb);
  hipLaunchKernelGGL(w1t_kernel, dim3(256), dim3(256), 0, stream, W1, W1t);
  hipLaunchKernelGGL(ulast_kernel, dim3(128), dim3(256), 0, stream, X, u_last);
  hipLaunchKernelGGL(gemm_score_kernel, dim3(1024), dim3(512), 0, stream,
                     Xb, W1t, b1, w2, scores);
  hipLaunchKernelGGL(attn_uatt_kernel, dim3(128, 2), dim3(256), 0, stream,
                     Xb, scores, mask, u_att);
}

// Round 3
// 256.000 us; speedup vs baseline: 1.2620x; 1.0414x over previous
//
#include <hip/hip_runtime.h>
#include <hip/hip_bf16.h>
#include <cstdint>
#include <cstddef>

// Problem constants (fixed by the reference)
#define BATCH 128
#define SEQ   512
#define DIM   1024
#define MROWS (BATCH * SEQ)          // 65536
#define NT    32                     // K sub-tiles of 32 (DIM/32)

typedef short short8 __attribute__((ext_vector_type(8)));
typedef __bf16 bf16x8 __attribute__((ext_vector_type(8)));
typedef float f32x4 __attribute__((ext_vector_type(4)));

// ---------- MFMA wrapper: accept either builtin signature (short8 or bf16x8) ----------
template <typename VA> struct other_frag { using type = bf16x8; };
template <> struct other_frag<bf16x8> { using type = short8; };

template <typename VA>
__device__ __forceinline__ auto try_mfma(VA a, VA b, f32x4 c, int)
    -> decltype(__builtin_amdgcn_mfma_f32_16x16x32_bf16(a, b, c, 0, 0, 0)) {
  return __builtin_amdgcn_mfma_f32_16x16x32_bf16(a, b, c, 0, 0, 0);
}
template <typename VA>
__device__ __forceinline__ f32x4 try_mfma(VA a, VA b, f32x4 c, long) {
  using O = typename other_frag<VA>::type;
  O a2 = __builtin_bit_cast(O, a);
  O b2 = __builtin_bit_cast(O, b);
  return __builtin_amdgcn_mfma_f32_16x16x32_bf16(a2, b2, c, 0, 0, 0);
}
__device__ __forceinline__ f32x4 mfma_bf16(short8 a, short8 b, f32x4 c) {
  return try_mfma(a, b, c, 0);
}

// ---------- helpers ----------
__device__ __forceinline__ unsigned short f32_to_bf16(float f) {
  union { float f; uint32_t u; } v; v.f = f;
  uint32_t u = v.u;
  u += 0x7FFFu + ((u >> 16) & 1u);   // round-to-nearest-even
  return (unsigned short)(u >> 16);
}

__device__ __forceinline__ short8 pack8(f32x4 a, f32x4 b) {
  short8 o;
  o[0] = (short)f32_to_bf16(a[0]); o[1] = (short)f32_to_bf16(a[1]);
  o[2] = (short)f32_to_bf16(a[2]); o[3] = (short)f32_to_bf16(a[3]);
  o[4] = (short)f32_to_bf16(b[0]); o[5] = (short)f32_to_bf16(b[1]);
  o[6] = (short)f32_to_bf16(b[2]); o[7] = (short)f32_to_bf16(b[3]);
  return o;
}

__device__ __forceinline__ void gload_lds16(const void* g, void* l) {
  __builtin_amdgcn_global_load_lds(
      (__attribute__((address_space(1))) void*)g,
      (__attribute__((address_space(3))) void*)l,
      16, 0, 0);
}

__device__ __forceinline__ float fast_tanh(float x) {
  x = fminf(fmaxf(x, -15.0f), 15.0f);
  float e = __expf(2.0f * x);
  return (e - 1.0f) / (e + 1.0f);
}

// ---------- kernel 1: W1 (D x D) -> W1t bf16 (transposed, [e][d]) ----------
__global__ __launch_bounds__(256) void w1t_kernel(const float* __restrict__ W1,
                                                  unsigned short* __restrict__ W1t) {
  __shared__ float tile[64][65];
  int bx = blockIdx.x & 15;    // e-tile
  int by = blockIdx.x >> 4;    // d-tile
  int t = threadIdx.x;
  int c = t & 63, r0 = t >> 6;
#pragma unroll
  for (int i = 0; i < 16; i++) {
    int r = i * 4 + r0;
    tile[r][c] = W1[(size_t)(by * 64 + r) * DIM + bx * 64 + c];
  }
  __syncthreads();
#pragma unroll
  for (int i = 0; i < 16; i++) {
    int r = i * 4 + r0;
    W1t[(size_t)(bx * 64 + r) * DIM + by * 64 + c] = f32_to_bf16(tile[c][r]);
  }
}

// ---------- kernel 2: fused GEMM (A = fp32 X, cast in-kernel) + tanh + w2-dot ----------
// C[m][e] = sum_d bf16(X[m][d]) * W1t[e][d]; scores[m] += sum_e tanh(C+b1[e])*w2[e]
//
// 256x256 tile, 8 waves (2M x 4N), wave-tile 128x64. K in subtiles of 32.
// Phase schedule (m201-style): per subtile 2 phases, each
//   {frag ds_reads + prefetch issue -> barrier -> 16 MFMA (setprio) -> barrier}.
// A: reg-staged from fp32 X (4 dwordx4 -> pack bf16 -> 2 ds_write), LDS dbuf 2x16KB.
// B: global_load_lds from W1t, LDS ring-3 3x16KB.  Total LDS 80 KB.
// One counted s_waitcnt vmcnt(5) per subtile at P1 (group-fenced; drains only in
// the 2 peeled tail subtiles).
//
// LDS 16KB buffer layout (logical [256 rows][32 k] bf16): row-pairs packed into
// 128-B stored rows; 16B chunk j of stored row sr holds logical
// (row = sr*2 + (j'>>2), k8 = j'&3) where j' = j ^ (sr&7).  2-way bank aliasing
// on ds_read_b128 (free), conflict-free writes/gloads (linear chunk order with
// source-side pre-swizzle).
__global__ __launch_bounds__(512, 2) void gemm_score_kernel(
    const float* __restrict__ Xf,             // [MROWS][DIM] fp32
    const unsigned short* __restrict__ W1t,   // [DIM][DIM]  (e-major)
    const float* __restrict__ b1,
    const float* __restrict__ w2,
    float* __restrict__ scores) {             // [MROWS]
  __shared__ __align__(16) char lds[81920];   // A: [0,32K)  B: [32K,80K)

  const int tid = threadIdx.x;
  const int lane = tid & 63;
  const int w = tid >> 6;                     // wave 0..7
  const int wr = w >> 2, wc = w & 3;          // 2 x 4 wave grid

  // chunked XCD swizzle: 1024 blocks, 8 XCDs, n-fastest within each chunk
  const int bx = blockIdx.x;
  const int swz = (bx & 7) * 128 + (bx >> 3);
  const int m0 = (swz >> 2) * 256;
  const int n0 = (swz & 3) * 256;

  // ---- A source (fp32, pre-swizzled). Thread's chunks i=0,1: sc=i*512+tid.
  // j = (tid&7)^((tid>>3)&7); logical row_i = i*128 + (tid>>3)*2 + (j>>2);
  // k8 = j&3 -> float offset (j&3)*8. Chunk = 8 floats = 2 dwordx4.
  const int j_sw = (tid & 7) ^ ((tid >> 3) & 7);
  const int ar0 = (tid >> 3) * 2 + (j_sw >> 2);
  const float* aS0 = Xf + (size_t)(m0 + ar0) * DIM + (j_sw & 3) * 8;

  // ---- B source (bf16 W1t, pre-swizzled), 2 gload_lds per subtile
  const unsigned short *b0Src, *b1Src;
  {
    int sr0 = tid >> 3, j0 = (tid & 7) ^ (sr0 & 7);
    int row0 = sr0 * 2 + (j0 >> 2), c40 = j0 & 3;
    b0Src = W1t + (size_t)(n0 + row0) * DIM + c40 * 8;
    int sc1 = 512 + tid;
    int sr1 = sc1 >> 3, j1 = (sc1 & 7) ^ (sr1 & 7);
    int row1 = sr1 * 2 + (j1 >> 2), c41 = j1 & 3;
    b1Src = W1t + (size_t)(n0 + row1) * DIM + c41 * 8;
  }

  // ---- fragment LDS byte offsets (within a 16KB buffer)
  int aOffL[4];
#pragma unroll
  for (int mi = 0; mi < 4; mi++) {
    int row = wr * 128 + mi * 16 + (lane & 15);
    int sr = row >> 1;
    int j = ((row & 1) * 4 + (lane >> 4)) ^ (sr & 7);
    aOffL[mi] = sr * 128 + j * 16;            // A47 offset = aOffL[mi] + 4096
  }
  int bOffL[4];
#pragma unroll
  for (int ni = 0; ni < 4; ni++) {
    int row = wc * 64 + ni * 16 + (lane & 15);
    int sr = row >> 1;
    int j = ((row & 1) * 4 + (lane >> 4)) ^ (sr & 7);
    bOffL[ni] = sr * 128 + j * 16;
  }

  f32x4 acc[8][4];
#pragma unroll
  for (int mi = 0; mi < 8; mi++)
#pragma unroll
    for (int ni = 0; ni < 4; ni++)
      acc[mi][ni] = (f32x4){0.f, 0.f, 0.f, 0.f};

  f32x4 rA0[4], rA1[4];
  short8 af[4], bf[4];

#define LOAD_A(SET, T) do {                                              \
    const float* aP_ = aS0 + (T) * 32;                                   \
    SET[0] = *(const f32x4*)(aP_);                                       \
    SET[1] = *(const f32x4*)(aP_ + 4);                                   \
    SET[2] = *(const f32x4*)(aP_ + (size_t)128 * DIM);                   \
    SET[3] = *(const f32x4*)(aP_ + (size_t)128 * DIM + 4);               \
  } while (0)

  // ---------- prologue: A(0),A(1) -> regs; B(0),B(1) -> LDS ----------
  LOAD_A(rA0, 0);
  __builtin_amdgcn_sched_barrier(0);
  gload_lds16(b0Src, lds + 32768 + w * 1024);
  gload_lds16(b1Src, lds + 32768 + 8192 + w * 1024);
  __builtin_amdgcn_sched_barrier(0);
  LOAD_A(rA1, 1);
  __builtin_amdgcn_sched_barrier(0);
  gload_lds16(b0Src + 32, lds + 32768 + 16384 + w * 1024);
  gload_lds16(b1Src + 32, lds + 32768 + 16384 + 8192 + w * 1024);
  __builtin_amdgcn_sched_barrier(0);
  asm volatile("s_waitcnt vmcnt(8)" ::: "memory");   // A(0) done
  {
    short8 w0 = pack8(rA0[0], rA0[1]);
    short8 w1 = pack8(rA0[2], rA0[3]);
    char* wd = lds + tid * 16;               // bufA[0]
    *(short8*)wd = w0;
    *(short8*)(wd + 8192) = w1;
  }
  asm volatile("s_waitcnt vmcnt(6)" ::: "memory");   // B(0) done
  asm volatile("s_waitcnt lgkmcnt(0)" ::: "memory"); // my A(0) writes drained
  __builtin_amdgcn_sched_barrier(0);
  __builtin_amdgcn_s_barrier();
  // entering loop, per-wave VMEM outstanding (oldest->newest): [A(1)x4, B(1)x2]

#define BODY(S, ISET, WSET, PF, DOWR, VMSTR) do {                        \
    /* ======== P0 ======== */                                           \
    if (PF) {                                                            \
      LOAD_A(ISET, (S) + 2);                                             \
      gload_lds16(b0Src + ((S) + 2) * 32,                                \
                  lds + 32768 + (((S) + 2) % 3) * 16384 + w * 1024);     \
    }                                                                    \
    __builtin_amdgcn_sched_barrier(0);                                   \
    {                                                                    \
      const char* bA_ = lds + ((S) & 1) * 16384;                         \
      const char* bB_ = lds + 32768 + ((S) % 3) * 16384;                 \
      af[0] = *(const short8*)(bA_ + aOffL[0]);                          \
      af[1] = *(const short8*)(bA_ + aOffL[1]);                          \
      af[2] = *(const short8*)(bA_ + aOffL[2]);                          \
      af[3] = *(const short8*)(bA_ + aOffL[3]);                          \
      bf[0] = *(const short8*)(bB_ + bOffL[0]);                          \
      bf[1] = *(const short8*)(bB_ + bOffL[1]);                          \
      bf[2] = *(const short8*)(bB_ + bOffL[2]);                          \
      bf[3] = *(const short8*)(bB_ + bOffL[3]);                          \
    }                                                                    \
    __builtin_amdgcn_sched_barrier(0);                                   \
    __builtin_amdgcn_s_barrier();                                        \
    __builtin_amdgcn_s_setprio(1);                                       \
    _Pragma("unroll")                                                    \
    for (int mi = 0; mi < 4; mi++)                                       \
      _Pragma("unroll")                                                  \
      for (int ni = 0; ni < 4; ni++)                                     \
        acc[mi][ni] = mfma_bf16(af[mi], bf[ni], acc[mi][ni]);            \
    __builtin_amdgcn_s_setprio(0);                                       \
    __builtin_amdgcn_s_barrier();                                        \
    /* ======== P1 ======== */                                           \
    asm volatile("s_waitcnt vmcnt(" VMSTR ")" ::: "memory");             \
    __builtin_amdgcn_sched_barrier(0);                                   \
    if (DOWR) {                                                          \
      short8 w0_ = pack8(WSET[0], WSET[1]);                              \
      short8 w1_ = pack8(WSET[2], WSET[3]);                              \
      char* wd_ = lds + (((S) + 1) & 1) * 16384 + tid * 16;              \
      *(short8*)wd_ = w0_;                                               \
      *(short8*)(wd_ + 8192) = w1_;                                      \
    }                                                                    \
    if (PF)                                                              \
      gload_lds16(b1Src + ((S) + 2) * 32,                                \
                  lds + 32768 + (((S) + 2) % 3) * 16384 + 8192 + w * 1024); \
    __builtin_amdgcn_sched_barrier(0);                                   \
    {                                                                    \
      const char* bA_ = lds + ((S) & 1) * 16384;                         \
      af[0] = *(const short8*)(bA_ + aOffL[0] + 4096);                   \
      af[1] = *(const short8*)(bA_ + aOffL[1] + 4096);                   \
      af[2] = *(const short8*)(bA_ + aOffL[2] + 4096);                   \
      af[3] = *(const short8*)(bA_ + aOffL[3] + 4096);                   \
    }                                                                    \
    __builtin_amdgcn_sched_barrier(0);                                   \
    __builtin_amdgcn_s_barrier();                                        \
    __builtin_amdgcn_s_setprio(1);                                       \
    _Pragma("unroll")                                                    \
    for (int mi = 0; mi < 4; mi++)                                       \
      _Pragma("unroll")                                                  \
      for (int ni = 0; ni < 4; ni++)                                     \
        acc[mi + 4][ni] = mfma_bf16(af[mi], bf[ni], acc[mi + 4][ni]);    \
    __builtin_amdgcn_s_setprio(0);                                       \
    __builtin_amdgcn_s_barrier();                                        \
  } while (0)

  for (int t = 0; t < 15; ++t) {
    const int S0 = 2 * t;
    BODY(S0, rA0, rA1, 1, 1, "5");
    BODY(S0 + 1, rA1, rA0, 1, 1, "5");
  }
  BODY(30, rA0, rA1, 0, 1, "0");
  BODY(31, rA1, rA0, 0, 0, "0");

#undef BODY
#undef LOAD_A

  // epilogue: scores[row] += sum over this wave's 64 cols of tanh(c + b1) * w2
  const int cg = lane >> 4;   // row group: rows cg*4 + j
  const int cl = lane & 15;   // col within fragment
#pragma unroll
  for (int mi = 0; mi < 8; mi++) {
    float p0 = 0.f, p1 = 0.f, p2 = 0.f, p3 = 0.f;
#pragma unroll
    for (int ni = 0; ni < 4; ni++) {
      int col = n0 + wc * 64 + ni * 16 + cl;
      float w2v = w2[col];
      float b1v = b1[col];
      p0 += fast_tanh(acc[mi][ni][0] + b1v) * w2v;
      p1 += fast_tanh(acc[mi][ni][1] + b1v) * w2v;
      p2 += fast_tanh(acc[mi][ni][2] + b1v) * w2v;
      p3 += fast_tanh(acc[mi][ni][3] + b1v) * w2v;
    }
#pragma unroll
    for (int off = 1; off < 16; off <<= 1) {
      p0 += __shfl_xor(p0, off);
      p1 += __shfl_xor(p1, off);
      p2 += __shfl_xor(p2, off);
      p3 += __shfl_xor(p3, off);
    }
    if (cl == 0) {
      int row = m0 + wr * 128 + mi * 16 + cg * 4;
      atomicAdd(&scores[row + 0], p0);
      atomicAdd(&scores[row + 1], p1);
      atomicAdd(&scores[row + 2], p2);
      atomicAdd(&scores[row + 3], p3);
    }
  }
}

// ---------- kernel 3: masked softmax + u_att + u_last (fp32 X) ----------
__global__ __launch_bounds__(256) void attn_uatt_kernel(
    const float* __restrict__ X,
    const float* __restrict__ scores,
    const int* __restrict__ mask,
    float* __restrict__ u_att,
    float* __restrict__ u_last) {
  const int b = blockIdx.x;
  const int half = blockIdx.y;            // d-range [half*512, half*512+512)
  const int tid = threadIdx.x;
  const int lane = tid & 63;
  const int wave = tid >> 6;

  __shared__ float attn[SEQ];
  __shared__ float rbuf[4];
  __shared__ float part[3][64 * 9];       // padded stride 9

  float s0 = scores[(size_t)b * SEQ + tid];
  float s1 = scores[(size_t)b * SEQ + 256 + tid];
  if (mask[(size_t)b * SEQ + tid]) s0 = -1000000000.0f;
  if (mask[(size_t)b * SEQ + 256 + tid]) s1 = -1000000000.0f;

  float mx = fmaxf(s0, s1);
#pragma unroll
  for (int off = 1; off < 64; off <<= 1) mx = fmaxf(mx, __shfl_xor(mx, off));
  if (lane == 0) rbuf[wave] = mx;
  __syncthreads();
  mx = fmaxf(fmaxf(rbuf[0], rbuf[1]), fmaxf(rbuf[2], rbuf[3]));

  float p0 = expf(s0 - mx), p1 = expf(s1 - mx);
  float sm = p0 + p1;
#pragma unroll
  for (int off = 1; off < 64; off <<= 1) sm += __shfl_xor(sm, off);
  __syncthreads();
  if (lane == 0) rbuf[wave] = sm;
  __syncthreads();
  sm = rbuf[0] + rbuf[1] + rbuf[2] + rbuf[3];
  float inv = 1.0f / sm;
  attn[tid] = p0 * inv;
  attn[tid + 256] = p1 * inv;
  __syncthreads();

  // u_last: exact fp32 copy of X[:, 511, :] (this block's 512-d half)
  if (tid < 128) {
    ((f32x4*)u_last)[(size_t)b * 256 + half * 128 + tid] =
        ((const f32x4*)X)[((size_t)b * SEQ + (SEQ - 1)) * 256 + half * 128 + tid];
  }

  // u_att[b][d] = sum_s attn[s] * X[b][s][d]; block covers 512 d (64 groups of 8)
  const int col = tid & 63;            // 8-float group within the half
  const int sh = tid >> 6;             // s-range split: [sh*128, sh*128+128)
  const f32x4* Xp = (const f32x4*)X + (size_t)b * SEQ * 256 + half * 128 + col * 2;
  f32x4 a0 = {0.f, 0.f, 0.f, 0.f}, a1 = {0.f, 0.f, 0.f, 0.f};
  for (int s = sh * 128; s < sh * 128 + 128; s++) {
    float wgt = attn[s];
    a0 += wgt * Xp[(size_t)s * 256];
    a1 += wgt * Xp[(size_t)s * 256 + 1];
  }
  if (sh) {
#pragma unroll
    for (int j = 0; j < 4; j++) part[sh - 1][col * 9 + j] = a0[j];
#pragma unroll
    for (int j = 0; j < 4; j++) part[sh - 1][col * 9 + 4 + j] = a1[j];
  }
  __syncthreads();
  if (sh == 0) {
#pragma unroll
    for (int j = 0; j < 4; j++)
      a0[j] += part[0][col * 9 + j] + part[1][col * 9 + j] + part[2][col * 9 + j];
#pragma unroll
    for (int j = 0; j < 4; j++)
      a1[j] += part[0][col * 9 + 4 + j] + part[1][col * 9 + 4 + j] + part[2][col * 9 + 4 + j];
    f32x4* dst = (f32x4*)(u_att + (size_t)b * DIM + half * 512 + col * 8);
    dst[0] = a0;
    dst[1] = a1;
  }
}

// ---------- launcher ----------
extern "C" void kernel_launch(void* const* d_in, const int* in_sizes, int n_in,
                              void* d_out, int out_size, void* d_ws, size_t ws_size,
                              hipStream_t stream) {
  const float* X    = (const float*)d_in[0];   // [128][512][1024] fp32
  const int*   mask = (const int*)d_in[1];     // [128][512] int32 (bool)
  const float* W1   = (const float*)d_in[2];   // [1024][1024]
  const float* b1   = (const float*)d_in[3];   // [1024]
  const float* w2   = (const float*)d_in[4];   // [1024]

  float* out    = (float*)d_out;
  float* u_last = out;                          // [128][1024]
  float* u_att  = out + BATCH * DIM;            // [128][1024]

  char* ws = (char*)d_ws;
  unsigned short* W1t = (unsigned short*)ws;                        // 2 MB
  float* scores = (float*)(ws + (size_t)DIM * DIM * 2);             // 256 KB

  hipMemsetAsync(scores, 0, MROWS * sizeof(float), stream);
  hipLaunchKernelGGL(w1t_kernel, dim3(256), dim3(256), 0, stream, W1, W1t);
  hipLaunchKernelGGL(gemm_score_kernel, dim3(1024), dim3(512), 0, stream,
                     X, W1t, b1, w2, scores);
  hipLaunchKernelGGL(attn_uatt_kernel, dim3(128, 2), dim3(256), 0, stream,
                     X, scores, mask, u_att, u_last);
}